// Round 10
// baseline (353.658 us; speedup 1.0000x reference)
//
#include <hip/hip_runtime.h>
#include <cstdint>
#include <cstddef>

typedef unsigned short u16;
typedef __attribute__((ext_vector_type(8))) short short8;
typedef __attribute__((ext_vector_type(4))) float v4f;

static constexpr size_t NN = (size_t)2048 * 2048;
#define N2 2048

typedef __attribute__((address_space(1))) const unsigned int guint;
typedef __attribute__((address_space(3))) unsigned int luint;

__device__ __forceinline__ float b2f_bits(uint32_t hi) { union { uint32_t u; float f; } v; v.u = hi; return v.f; }
__device__ __forceinline__ float b2f(u16 x) { return b2f_bits((uint32_t)x << 16); }
__device__ __forceinline__ u16 f2b(float f) {
  union { float f; uint32_t u; } v; v.f = f;
  uint32_t r = v.u + 0x7fffu + ((v.u >> 16) & 1u);
  return (u16)(r >> 16);
}
__device__ __forceinline__ uint2 pack4(const float* f) {
  uint2 u;
  u.x = (uint32_t)f2b(f[0]) | ((uint32_t)f2b(f[1]) << 16);
  u.y = (uint32_t)f2b(f[2]) | ((uint32_t)f2b(f[3]) << 16);
  return u;
}
__device__ __forceinline__ uint4 pack8(const float* f) {
  uint4 u;
  u.x = (uint32_t)f2b(f[0]) | ((uint32_t)f2b(f[1]) << 16);
  u.y = (uint32_t)f2b(f[2]) | ((uint32_t)f2b(f[3]) << 16);
  u.z = (uint32_t)f2b(f[4]) | ((uint32_t)f2b(f[5]) << 16);
  u.w = (uint32_t)f2b(f[6]) | ((uint32_t)f2b(f[7]) << 16);
  return u;
}
__device__ __forceinline__ void unpack8u(uint4 u, float* f) {
  f[0] = b2f_bits(u.x << 16); f[1] = b2f_bits(u.x & 0xffff0000u);
  f[2] = b2f_bits(u.y << 16); f[3] = b2f_bits(u.y & 0xffff0000u);
  f[4] = b2f_bits(u.z << 16); f[5] = b2f_bits(u.z & 0xffff0000u);
  f[6] = b2f_bits(u.w << 16); f[7] = b2f_bits(u.w & 0xffff0000u);
}
__device__ __forceinline__ uint4 add_bf16x8(uint4 a, uint4 b) {
  float fa[8], fb[8], s[8];
  unpack8u(a, fa); unpack8u(b, fb);
  #pragma unroll
  for (int u = 0; u < 8; ++u) s[u] = fa[u] + fb[u];
  return pack8(s);
}

// ---------------------------------------------------------------------------
// K0: one pass over fp32 A[5][N][N]: softmax-weighted sums -> abf (bf16,
// row-major), bbt = b^T, a1t = a1^T (bf16 via LDS-tiled transpose).
// 32x32 tiles, 4096 blocks. Blocks with by<8 additionally compute
// Xwt[k][n] = bf16( (X @ W)[n][k] ).
// ---------------------------------------------------------------------------
__global__ __launch_bounds__(256, 6) void conv_kernel(
    const float* __restrict__ A, const float* __restrict__ w1,
    const float* __restrict__ w2, const float* __restrict__ w3,
    const float* __restrict__ X, const float* __restrict__ W,
    u16* __restrict__ abf, u16* __restrict__ bbt, u16* __restrict__ a1t,
    u16* __restrict__ Xwt)
{
  __shared__ float lb[32][33];
  __shared__ float la[32][33];
  const int t = threadIdx.x;
  const int i0 = blockIdx.y * 32, j0 = blockIdx.x * 32;

  float s1[2][5], s2[2][5], s3[2][5];
  {
    const float* wsrc[3] = { w1, w2, w3 };
    float (*sdst[3])[5] = { s1, s2, s3 };
    for (int q = 0; q < 3; ++q)
      for (int c = 0; c < 2; ++c) {
        float v[5], m = -1e30f, sum = 0.f;
        for (int e = 0; e < 5; ++e) { v[e] = wsrc[q][c * 5 + e]; m = fmaxf(m, v[e]); }
        for (int e = 0; e < 5; ++e) { v[e] = expf(v[e] - m); sum += v[e]; }
        for (int e = 0; e < 5; ++e) sdst[q][c][e] = v[e] / sum;
      }
  }

  const int row = t >> 3;         // 0..31
  const int c4 = (t & 7) * 4;     // col base within tile
  float cst[2][4];                // a1 stash

  {
    float fa[5][4];
    for (int e = 0; e < 5; ++e) {
      float4 v = *(const float4*)(A + (size_t)e * NN + (size_t)(i0 + row) * N2 + (j0 + c4));
      fa[e][0] = v.x; fa[e][1] = v.y; fa[e][2] = v.z; fa[e][3] = v.w;
    }
    for (int c = 0; c < 2; ++c) {
      float av[4] = {0,0,0,0}, bv[4] = {0,0,0,0}, cv[4] = {0,0,0,0};
      for (int e = 0; e < 5; ++e)
        #pragma unroll
        for (int u = 0; u < 4; ++u) {
          av[u] += s1[c][e] * fa[e][u];
          bv[u] += s2[c][e] * fa[e][u];
          cv[u] += s3[c][e] * fa[e][u];
        }
      *(uint2*)(abf + (size_t)c * NN + (size_t)(i0 + row) * N2 + (j0 + c4)) = pack4(av);
      float* ldst = (c == 0) ? &lb[row][c4] : &la[row][c4];
      #pragma unroll
      for (int u = 0; u < 4; ++u) ldst[u] = bv[u];
      #pragma unroll
      for (int u = 0; u < 4; ++u) cst[c][u] = cv[u];
    }
  }
  __syncthreads();
  {
    float t0[4], t1[4];
    #pragma unroll
    for (int u = 0; u < 4; ++u) { t0[u] = lb[c4 + u][row]; t1[u] = la[c4 + u][row]; }
    *(uint2*)(bbt + 0 * NN + (size_t)(j0 + row) * N2 + (i0 + c4)) = pack4(t0);
    *(uint2*)(bbt + 1 * NN + (size_t)(j0 + row) * N2 + (i0 + c4)) = pack4(t1);
  }
  __syncthreads();
  #pragma unroll
  for (int u = 0; u < 4; ++u) { lb[row][c4 + u] = cst[0][u]; la[row][c4 + u] = cst[1][u]; }
  __syncthreads();
  {
    float t0[4], t1[4];
    #pragma unroll
    for (int u = 0; u < 4; ++u) { t0[u] = lb[c4 + u][row]; t1[u] = la[c4 + u][row]; }
    *(uint2*)(a1t + 0 * NN + (size_t)(j0 + row) * N2 + (i0 + c4)) = pack4(t0);
    *(uint2*)(a1t + 1 * NN + (size_t)(j0 + row) * N2 + (i0 + c4)) = pack4(t1);
  }
  // Folded Xw^T compute: 512 blocks x 4 rows = 2048 rows.
  if (blockIdx.y < 8) {
    const int n = (int)(blockIdx.y * 64 + blockIdx.x) * 4 + (t >> 6);
    const int k = t & 63;
    float acc = 0.f;
    for (int m = 0; m < 256; ++m)
      acc += X[n * 256 + m] * W[m * 64 + k];
    Xwt[(size_t)k * N2 + n] = f2b(acc);
  }
}

// ---------------------------------------------------------------------------
// bf16 MFMA GEMM, SPLIT-K=2 (z = c*2+split... actually z: c=z>>1, split=z&1).
// Each block: 128x64 tile, K-range [split*1024, split*1024+1024), BK=64,
// glds staging. Grid (32,16,4) = 2048 blocks -> ~6 resident blocks/CU.
// Outputs (all PARTIAL per split):
//   Cout + (split*2+c)*NN : bf16 partial (row-major if !TOUT, transposed if TOUT)
//   csp[(c*32)+split*16+by][n0..]: fp32 partial column sums (from registers)
//   diagp[(split*2+c)*2048+q]:     fp32 partial diagonal
// ---------------------------------------------------------------------------
template<bool TOUT>
__global__ __launch_bounds__(256, 6) void gemm_kernel(
    const u16* __restrict__ Ain, const u16* __restrict__ Btin,
    u16* __restrict__ Cout, float* __restrict__ csp, float* __restrict__ diagp)
{
  const int c = (int)blockIdx.z >> 1, split = (int)blockIdx.z & 1;
  const u16* Ac = Ain + (size_t)c * NN;
  const u16* Bc = Btin + (size_t)c * NN;
  const int m0 = blockIdx.y * 128, n0 = blockIdx.x * 64;
  const int t = threadIdx.x, w = t >> 6, lane = t & 63;
  const int quad = lane >> 4, r = lane & 15;
  __shared__ u16 SM[128 * 64 + 64 * 64];   // As | Bs (24 KB)
  u16* As = SM;
  u16* Bs = SM + 128 * 64;

  v4f zero4 = { 0.f, 0.f, 0.f, 0.f };
  v4f acc[2][4];
  #pragma unroll
  for (int i = 0; i < 2; ++i)
    #pragma unroll
    for (int j = 0; j < 4; ++j) acc[i][j] = zero4;

  const int srow = lane >> 3;            // row within an 8-row chunk
  const int sgran = (lane & 7) ^ srow;   // swizzled k-granule

  const int koff = split << 10;
  for (int kt = koff; kt < koff + 1024; kt += 64) {
    __syncthreads();
    #pragma unroll
    for (int i = 0; i < 4; ++i) {
      const int chunk = i * 4 + w;
      const u16* ga = Ac + (size_t)(m0 + chunk * 8 + srow) * N2 + kt + sgran * 8;
      __builtin_amdgcn_global_load_lds((guint*)ga, (luint*)(As + chunk * 512), 16, 0, 0);
    }
    #pragma unroll
    for (int i = 0; i < 2; ++i) {
      const int chunk = i * 4 + w;
      const u16* gb = Bc + (size_t)(n0 + chunk * 8 + srow) * N2 + kt + sgran * 8;
      __builtin_amdgcn_global_load_lds((guint*)gb, (luint*)(Bs + chunk * 512), 16, 0, 0);
    }
    __syncthreads();
    #pragma unroll
    for (int ks = 0; ks < 2; ++ks) {
      const int sl = ((ks * 4 + quad) ^ (r & 7)) * 8;
      short8 af[2], bf[4];
      #pragma unroll
      for (int i = 0; i < 2; ++i)
        af[i] = *(const short8*)(As + (w * 32 + i * 16 + r) * 64 + sl);
      #pragma unroll
      for (int j = 0; j < 4; ++j)
        bf[j] = *(const short8*)(Bs + (j * 16 + r) * 64 + sl);
      #pragma unroll
      for (int i = 0; i < 2; ++i)
        #pragma unroll
        for (int j = 0; j < 4; ++j)
          acc[i][j] = __builtin_amdgcn_mfma_f32_16x16x32_bf16(af[i], bf[j], acc[i][j], 0, 0, 0);
    }
  }
  // C/D layout: col=lane&15, row=quad*4+reg (m89-verified).
  u16* Cc = Cout + (size_t)(split * 2 + c) * NN;
  // Partial diagonal (fp32).
  if ((int)(blockIdx.x >> 1) == (int)blockIdx.y) {
    #pragma unroll
    for (int i = 0; i < 2; ++i) {
      const int rowg = m0 + w * 32 + i * 16 + quad * 4;
      #pragma unroll
      for (int j = 0; j < 4; ++j) {
        const int colg = n0 + j * 16 + r;
        #pragma unroll
        for (int g = 0; g < 4; ++g)
          if (rowg + g == colg) diagp[(split * 2 + c) * N2 + colg] = acc[i][j][g];
      }
    }
  }
  if constexpr (!TOUT) {
    #pragma unroll
    for (int i = 0; i < 2; ++i) {
      const int rowg = m0 + w * 32 + i * 16 + quad * 4;
      #pragma unroll
      for (int j = 0; j < 4; ++j) {
        const int colg = n0 + j * 16 + r;
        #pragma unroll
        for (int g = 0; g < 4; ++g)
          Cc[(size_t)(rowg + g) * N2 + colg] = f2b(acc[i][j][g]);
      }
    }
  }
  // Partial column sums over this block's 128 rows for its 64 cols.
  float s[4];
  #pragma unroll
  for (int j = 0; j < 4; ++j) {
    s[j] = 0.f;
    #pragma unroll
    for (int i = 0; i < 2; ++i)
      #pragma unroll
      for (int g = 0; g < 4; ++g) s[j] += acc[i][j][g];
    s[j] += __shfl_xor(s[j], 16);
    s[j] += __shfl_xor(s[j], 32);
  }
  __syncthreads();                 // MFMA-loop LDS reads done
  float* csl = (float*)SM;         // [4][64]
  if (quad == 0) {
    #pragma unroll
    for (int j = 0; j < 4; ++j) csl[w * 64 + j * 16 + r] = s[j];
  }
  __syncthreads();
  if (t < 64) {
    const float v = csl[t] + csl[64 + t] + csl[128 + t] + csl[192 + t];
    csp[((size_t)(c * 32) + split * 16 + blockIdx.y) * N2 + n0 + t] = v;
  }
  if constexpr (TOUT) {
    // Transpose tile via LDS (row stride 136 u16 = 272 B, 16-B aligned rows).
    // Each thread stores a FULL 32-u16 segment (4x uint4): 64x4x32 = 8192 ✓.
    __syncthreads();
    u16* tb = SM;                  // [64][136] u16 = 17.4 KB
    #pragma unroll
    for (int i = 0; i < 2; ++i) {
      #pragma unroll
      for (int j = 0; j < 4; ++j) {
        #pragma unroll
        for (int g = 0; g < 4; ++g)
          tb[(j * 16 + r) * 136 + (w * 32 + i * 16 + quad * 4 + g)] = f2b(acc[i][j][g]);
      }
    }
    __syncthreads();
    const int rown = t >> 2, seg = t & 3;
    const u16* ps = tb + rown * 136 + seg * 32;
    uint4* pd = (uint4*)(Cc + (size_t)(n0 + rown) * N2 + m0 + seg * 32);
    pd[0] = ((const uint4*)ps)[0];
    pd[1] = ((const uint4*)ps)[1];
    pd[2] = ((const uint4*)ps)[2];
    pd[3] = ((const uint4*)ps)[3];
  }
}

// colinv[c][q] = 1/(deg+eps), deg = sum_{s<32} csp - (diag split0 + split1)
__global__ void colinv_kernel(const float* __restrict__ csp, const float* __restrict__ diagp, float* __restrict__ ci)
{
  const int idx = blockIdx.x * 256 + threadIdx.x;  // [0, 4096)
  float cs = 0.f;
  const int c = idx >> 11, q = idx & 2047;
  #pragma unroll
  for (int s = 0; s < 32; ++s) cs += csp[((size_t)(c * 32) + s) * N2 + q];
  const float deg = cs - diagp[c * N2 + q] - diagp[(2 + c) * N2 + q];
  ci[idx] = (deg == 0.f) ? 0.f : 1.f / (deg + 1e-8f);
}

// Hn[p][q] = bf16( p==q ? 0 : ci[q]*(P0[p][q]+P1[p][q]) ) — fused split-reduce.
__global__ __launch_bounds__(256) void scale_kernel(const u16* __restrict__ H1p, const float* __restrict__ ci, u16* __restrict__ Hn)
{
  const int idx = blockIdx.x * 256 + threadIdx.x;
  const int q0 = (idx & 255) * 8;
  const int p = (idx >> 8) & 2047;
  const int c = idx >> 19;
  const size_t off = (size_t)p * N2 + q0;
  uint4 u0 = *(const uint4*)(H1p + (size_t)c * NN + off);
  uint4 u1 = *(const uint4*)(H1p + (size_t)(2 + c) * NN + off);
  const float* cv = ci + c * N2 + q0;
  float h0[8], h1[8], f[8];
  unpack8u(u0, h0); unpack8u(u1, h1);
  #pragma unroll
  for (int u = 0; u < 8; ++u) {
    float v = (h0[u] + h1[u]) * cv[u];
    f[u] = (q0 + u == p) ? 0.f : v;
  }
  *(uint4*)(Hn + (size_t)c * NN + off) = pack8(f);
}

// ---------------------------------------------------------------------------
// T-partials via MFMA: A = H2t (sum of 2 bf16 split-partials, added during
// staging), B = Xwt via glds. M=2048, N=64, K=2048, K-split 16 (blockIdx.y).
// Grid (16 m-tiles, 16 splits, 2 c) = 512 blocks.
// ---------------------------------------------------------------------------
__global__ __launch_bounds__(256) void tgemm_kernel(
    const u16* __restrict__ H2tp, const u16* __restrict__ Xwt, float* __restrict__ Tp)
{
  const int c = blockIdx.z, jsplit = blockIdx.y;
  const int m0 = blockIdx.x * 128;
  const u16* P0 = H2tp + (size_t)c * NN;
  const u16* P1 = H2tp + (size_t)(2 + c) * NN;
  const int t = threadIdx.x, w = t >> 6, lane = t & 63;
  const int quad = lane >> 4, r = lane & 15;
  __shared__ u16 As[128 * 64];
  __shared__ u16 Bs[64 * 64];

  v4f zero4 = { 0.f, 0.f, 0.f, 0.f };
  v4f acc[2][4];
  #pragma unroll
  for (int i = 0; i < 2; ++i)
    #pragma unroll
    for (int j = 0; j < 4; ++j) acc[i][j] = zero4;

  const int srow = lane >> 3;
  const int sgran = (lane & 7) ^ srow;

  for (int kk = 0; kk < 2; ++kk) {
    const int kt = jsplit * 128 + kk * 64;
    __syncthreads();
    #pragma unroll
    for (int i = 0; i < 2; ++i) {
      const int chunk = i * 4 + w;
      const u16* gb = Xwt + (size_t)(chunk * 8 + srow) * N2 + kt + sgran * 8;
      __builtin_amdgcn_global_load_lds((guint*)gb, (luint*)(Bs + chunk * 512), 16, 0, 0);
    }
    #pragma unroll
    for (int i = 0; i < 4; ++i) {
      const int chunk = i * 4 + w;
      const size_t off = (size_t)(m0 + chunk * 8 + srow) * N2 + kt + sgran * 8;
      uint4 va = add_bf16x8(*(const uint4*)(P0 + off), *(const uint4*)(P1 + off));
      *(uint4*)(As + chunk * 512 + lane * 8) = va;
    }
    __syncthreads();
    #pragma unroll
    for (int ks = 0; ks < 2; ++ks) {
      const int sl = ((ks * 4 + quad) ^ (r & 7)) * 8;
      short8 af[2], bf[4];
      #pragma unroll
      for (int i = 0; i < 2; ++i)
        af[i] = *(const short8*)(As + (w * 32 + i * 16 + r) * 64 + sl);
      #pragma unroll
      for (int j = 0; j < 4; ++j)
        bf[j] = *(const short8*)(Bs + (j * 16 + r) * 64 + sl);
      #pragma unroll
      for (int i = 0; i < 2; ++i)
        #pragma unroll
        for (int j = 0; j < 4; ++j)
          acc[i][j] = __builtin_amdgcn_mfma_f32_16x16x32_bf16(af[i], bf[j], acc[i][j], 0, 0, 0);
    }
  }
  const size_t pbase = (size_t)(jsplit * 2 + c) * 2048;
  #pragma unroll
  for (int i = 0; i < 2; ++i) {
    const int rowg = m0 + w * 32 + i * 16 + quad * 4;
    #pragma unroll
    for (int j = 0; j < 4; ++j) {
      const int colg = j * 16 + r;
      #pragma unroll
      for (int g = 0; g < 4; ++g)
        Tp[(pbase + rowg + g) * 64 + colg] = acc[i][j][g];
    }
  }
}

// out[i][c*64+k] = relu( dinv * (T - hd*xw + xw) ), fp32
__global__ void epilogue_kernel(const float* __restrict__ Tp, const float* __restrict__ cspb,
                                const float* __restrict__ diag2p, const u16* __restrict__ Xwt,
                                float* __restrict__ out)
{
  const int idx = blockIdx.x * 256 + threadIdx.x;
  const int k = idx & 63;
  const int c = (idx >> 6) & 1;
  const int i = idx >> 7;
  float T = 0.f, cs = 0.f;
  #pragma unroll
  for (int s = 0; s < 16; ++s)
    T += Tp[((size_t)(s * 2 + c) * 2048 + i) * 64 + k];
  #pragma unroll
  for (int s = 0; s < 32; ++s)
    cs += cspb[((size_t)(c * 32) + s) * N2 + i];
  const float hd = diag2p[c * N2 + i] + diag2p[(2 + c) * N2 + i];
  const float xw = b2f(Xwt[(size_t)k * N2 + i]);
  const float deg = cs - hd + 1.0f;  // add=True: diag set to 1 contributes +1
  const float dinv = (deg == 0.f) ? 0.f : 1.f / (deg + 1e-8f);
  float v = dinv * (T - hd * xw + xw);
  v = v > 0.f ? v : 0.f;
  out[(size_t)i * 128 + c * 64 + k] = v;
}

// ---------------------------------------------------------------------------
// Workspace layout (bytes), peak ~85.3 MB, all reads preceded by writes:
//   abf   @ 0          (16.78 MB bf16)  -- dead after gemm1
//   bbt   @ 16777216   (16.78 MB bf16)  -- dead after gemm1
//   a1t   @ 33554432   (16.78 MB bf16)  -- dead after gemm2
//   H1p   @ 50331648   (33.55 MB bf16 [split][c][N][N]) -- dead after scale
//   Hn    @ 16777216   (16.78 MB bf16, over bbt; written by scale)
//   H2tp  @ 0 / 50331648 (2x16.78 MB bf16 split-partials of H2^T;
//                         over abf and H1p-split0)
//   Tp    @ 67108864   (16.78 MB fp32, over H1p-split1)
//   Xwt   @ 83886080   (256 KB bf16 [64][2048])
//   cspa  @ 84148224   (512 KB [2][32][2048] fp32)
//   cspb  @ 84672512   (512 KB)
//   diag1p@ 85196800   (32 KB [split][c][2048] fp32)
//   diag2p@ 85229568   (32 KB)
//   ci1   @ 85262336   (16 KB)          -- end 85278720
// ---------------------------------------------------------------------------
extern "C" void kernel_launch(void* const* d_in, const int* in_sizes, int n_in,
                              void* d_out, int out_size, void* d_ws, size_t ws_size,
                              hipStream_t stream) {
  const float* A  = (const float*)d_in[0];
  const float* X  = (const float*)d_in[1];
  const float* w1 = (const float*)d_in[2];
  const float* w2 = (const float*)d_in[3];
  const float* w3 = (const float*)d_in[4];
  const float* W  = (const float*)d_in[5];
  float* out = (float*)d_out;
  char* ws = (char*)d_ws;

  u16*   abf    = (u16*)(ws + 0);
  u16*   bbt    = (u16*)(ws + 16777216);
  u16*   a1t    = (u16*)(ws + 33554432);
  u16*   H1p    = (u16*)(ws + 50331648);   // [split][c] bf16 partials
  u16*   Hn     = (u16*)(ws + 16777216);   // over bbt
  u16*   H2tp   = (u16*)(ws + 0);          // split0 @0 (over abf)
  // split1 of H2tp lives at ws+50331648 (over H1p split0): gemm2 writes
  // (split*2+c)*NN u16 from its base, so base must satisfy base+2*NN*2 = 50331648
  // -> base = ws + 0 works: split0 offsets 0..2NN, split1 offsets 2NN..4NN
  // = bytes 33554432..67108864. BUT a1t lives at 33554432 and is read by gemm2!
  // So instead pass H2tp base = ws+0 with split1 redirected via layout:
  // we keep the natural (split*2+c)*NN indexing but allocate H2tp as a single
  // 4*NN u16 region at ws+0 is NOT possible (a1t conflict). Solution: gemm2's
  // Cout base = ws + 0 for split0/ c in {0,1} (offsets 0..33554432 over abf+bbt)
  // -- but Hn occupies 16777216..33554432. Conflict!
  // => Final safe layout: H2tp occupies a dedicated region over H1p:
  //    base = ws + 50331648 (H1p dead after scale; gemm2 runs after scale).
  float* Tp     = (float*)(ws + 83886080 + 262144 + 1048576 + 65536 + 16384);
  u16*   Xwt    = (u16*)(ws + 83886080);
  float* cspa   = (float*)(ws + 84148224);
  float* cspb   = (float*)(ws + 84672512);
  float* diag1p = (float*)(ws + 85196800);
  float* diag2p = (float*)(ws + 85229568);
  float* ci1    = (float*)(ws + 85262336);
  u16*   H2tpB  = (u16*)(ws + 50331648);   // [split][c] bf16 partials of H2^T
  Tp            = (float*)(ws + 85278720); // 16.78 MB fp32, end ~102.06 MB... too big?
  // Keep Tp within proven budget: place Tp over abf+bbt-first-half instead:
  // abf dead after gemm1, Hn occupies 16777216..33554432 (live through gemm2),
  // Tp (16.78 MB) fits at ws+0..16777216? Only 16.78 MB needed. Hn untouched. OK:
  Tp            = (float*)(ws + 0);        // over abf (dead); tgemm runs after gemm2

  conv_kernel<<<dim3(64, 64), 256, 0, stream>>>(A, w1, w2, w3, X, W, abf, bbt, a1t, Xwt);
  gemm_kernel<false><<<dim3(32, 16, 4), 256, 0, stream>>>(abf, bbt, H1p, cspa, diag1p);
  colinv_kernel<<<16, 256, 0, stream>>>(cspa, diag1p, ci1);
  scale_kernel<<<4096, 256, 0, stream>>>(H1p, ci1, Hn);
  gemm_kernel<true><<<dim3(32, 16, 4), 256, 0, stream>>>(Hn, a1t, H2tpB, cspb, diag2p);
  tgemm_kernel<<<dim3(16, 16, 2), 256, 0, stream>>>(H2tpB, Xwt, Tp);
  epilogue_kernel<<<1024, 256, 0, stream>>>(Tp, cspb, diag2p, Xwt, out);
}